// Round 1
// baseline (205.006 us; speedup 1.0000x reference)
//
#include <hip/hip_runtime.h>

// Signature-kernel MMD via Goursat PDE — round 3.
// Round-2 postmortem: (1) grid 2112 blocks vs 2048-block co-residency
// capacity -> second near-empty dispatch round (Occupancy 48%). (2)
// VGPR_Count=28 < 32 floats of dY fragments -> compiler sank the dY loads
// into the 127-row loop (8 reloads/row from L1/L2), VALUBusy capped at 68%.
// Round-3: exact-capacity grid (2048 blocks = 8192 waves, 64 waves at
// stride 129 take one extra task), asm-pinned dY registers, ping-pong SGPR
// dX rows, reduction fused via per-block atomicAdd.

#define DINC_PER 130048                         // 64*127*16 floats
#define NWAVES 8192
#define NTASK 8256                              // 4096 XY + 2*2080 tri
#define NBLOCKS3 2048

template <int C, int RM, int BM, bool BC>
__device__ __forceinline__ float dpp0(float x) {
    return __builtin_bit_cast(float, __builtin_amdgcn_update_dpp(
        0, __builtin_bit_cast(int, x), C, RM, BM, BC));
}

// 64-lane inclusive prefix sum, pure VALU (6 dependent adds).
__device__ __forceinline__ float wave_scan_incl(float v) {
    v += dpp0<0x111, 0xf, 0xf, true>(v);   // row_shr:1
    v += dpp0<0x112, 0xf, 0xf, true>(v);   // row_shr:2
    v += dpp0<0x114, 0xf, 0xf, true>(v);   // row_shr:4
    v += dpp0<0x118, 0xf, 0xf, true>(v);   // row_shr:8
    v += dpp0<0x142, 0xa, 0xf, false>(v);  // row_bcast:15 -> rows 1,3
    v += dpp0<0x143, 0xc, 0xf, false>(v);  // row_bcast:31 -> rows 2,3
    return v;
}

// lane l gets lane l-1's x; lane 0 gets `oldv`.
__device__ __forceinline__ float wave_shr1(float x, float oldv) {
    return __builtin_bit_cast(float, __builtin_amdgcn_update_dpp(
        __builtin_bit_cast(int, oldv), __builtin_bit_cast(int, x),
        0x138, 0xf, 0xf, false));          // wave_shr:1
}

// ---- kernel 1: path increments X,Y -> ws (dX at 0, dY at DINC_PER) ----
// Also zeroes out[0] for the fused atomic reduction in sig_pde3.
__global__ __launch_bounds__(256) void sig_diff(
    const float* __restrict__ X, const float* __restrict__ Y,
    float* __restrict__ dInc, float* __restrict__ out)
{
    if (blockIdx.x == 0 && threadIdx.x == 0) out[0] = 0.0f;
    int i = blockIdx.x * 256 + threadIdx.x;   // float4 id, 65024 total
    if (i >= 65024) return;
    int which = (i >= 32512) ? 1 : 0;
    int j = i - which * 32512;
    int a = j / 508;                          // 127*4 float4 per path
    int rq = j - a * 508;                     // r*4 + q
    const float* S = which ? Y : X;
    const float4* p = (const float4*)(S + a * 2048) + rq;
    float4 v0 = p[0], v1 = p[4];              // +16 floats = next row
    float4 d;
    d.x = v1.x - v0.x; d.y = v1.y - v0.y;
    d.z = v1.z - v0.z; d.w = v1.w - v0.w;
    ((float4*)dInc)[i] = d;
}

// ---- kernel 2: PDE. 2048 blocks * 4 waves = 8192 waves, task ids flat.
// Tasks 8192..8255 are second tasks of waves gw%129==0 (spread over CUs).
__global__ __launch_bounds__(256, 8) void sig_pde3(
    const float* __restrict__ dInc, float* __restrict__ out)
{
    __shared__ float red[4];
    const int wid  = threadIdx.x >> 6;
    const int lane = threadIdx.x & 63;
    const int gw   = (blockIdx.x << 2) + wid;

    float acc = 0.0f;
    const int nextra = ((gw % 129) == 0) ? 1 : 0;

#pragma unroll 1
    for (int it = 0; it <= nextra; ++it) {
        const int t = it ? (NWAVES + gw / 129) : gw;

        // decode flat task id -> (gram g, a, b); wave-uniform scalar work
        int g, a, b;
        if (t < 4096) {                        // XY: dense 64x64
            g = 2; a = t >> 6; b = t & 63;
        } else {                               // XX / YY upper triangles
            int tt = t - 4096;
            g = 0;
            if (tt >= 2080) { g = 1; tt -= 2080; }
            int aa = 0;
            for (;;) { int nb = 64 - aa; if (tt < nb) break; tt -= nb; ++aa; }
            a = aa; b = aa + tt;
        }

        const float* dA = (g == 1) ? (dInc + DINC_PER) : dInc;   // row paths
        const float* dB = (g == 0) ? dInc : (dInc + DINC_PER);   // col paths
        const float weight = (g == 2) ? (-2.0f / 4096.0f)
                                      : ((a == b ? 1.0f : 2.0f) / 4096.0f);

        // per-lane dY rows j=2l, 2l+1 (lane 63's second row masked via c1)
        float ya[16], yb_[16];
        {
            const float* Qb = dB + b * 2032;
            const int j0 = lane << 1;
            const int j1 = (j0 + 1 < 127) ? j0 + 1 : 126;
            const float4* A4 = (const float4*)(Qb + j0 * 16);
            const float4* B4 = (const float4*)(Qb + j1 * 16);
#pragma unroll
            for (int q = 0; q < 4; ++q) {
                float4 va = A4[q], vb = B4[q];
                ya[4*q+0]=va.x;  ya[4*q+1]=va.y;  ya[4*q+2]=va.z;  ya[4*q+3]=va.w;
                yb_[4*q+0]=vb.x; yb_[4*q+1]=vb.y; yb_[4*q+2]=vb.z; yb_[4*q+3]=vb.w;
            }
        }
        // Pin the fragments into VGPRs: the asm is opaque, so the compiler
        // cannot re-sink these loads into the row loop (round-2 bug:
        // VGPR_Count=28 proved it reloaded 8x dwordx4 every row).
#pragma unroll
        for (int d = 0; d < 16; ++d)
            asm volatile("" : "+v"(ya[d]), "+v"(yb_[d]));

        // block... wave-uniform dX base -> s_load rows into SGPRs
        const int abase = __builtin_amdgcn_readfirstlane(a * 2032);
        const float4* Ar = (const float4*)(dA + abase);

        float xr[16], xn[16];
#pragma unroll
        for (int q = 0; q < 4; ++q) {
            float4 v = Ar[q];
            xr[4*q+0]=v.x; xr[4*q+1]=v.y; xr[4*q+2]=v.z; xr[4*q+3]=v.w;
        }

        float g_lo = 1.0f, g_hi = 1.0f;        // G[r][2l+1], G[r][2l+2]
        const bool last = (lane == 63);

#define SIG_ROW(XROW)                                                       \
        {                                                                   \
            float s0=-0.5f, s1=-0.5f, t0=-0.5f, t1=-0.5f;                   \
            _Pragma("unroll")                                               \
            for (int d = 0; d < 16; d += 2) {                               \
                s0 = fmaf(XROW[d],   ya[d],    s0);                         \
                s1 = fmaf(XROW[d+1], ya[d+1],  s1);                         \
                t0 = fmaf(XROW[d],   yb_[d],   t0);                         \
                t1 = fmaf(XROW[d+1], yb_[d+1], t1);                         \
            }                                                               \
            const float i0 = s0 + s1;          /* inc(r, 2l)   - 1 */       \
            const float i1 = t0 + t1;          /* inc(r, 2l+1) - 1 */       \
            const float gl = wave_shr1(g_hi, 1.0f);  /* G[r][2l] */         \
            const float c0 = fmaf(gl, i0, g_lo);                            \
            const float c1 = last ? 0.0f : fmaf(g_lo, i1, g_hi);            \
            const float S  = wave_scan_incl(c0 + c1);                       \
            g_lo = (S - c1) + 1.0f;                                         \
            g_hi = S + 1.0f;                                                \
        }

        // ping-pong SGPR row buffers: no per-row copy, 1-row prefetch depth
#pragma unroll 1
        for (int r = 0; r < 126; r += 2) {
#pragma unroll
            for (int q = 0; q < 4; ++q) {
                float4 v = Ar[4*(r+1)+q];
                xn[4*q+0]=v.x; xn[4*q+1]=v.y; xn[4*q+2]=v.z; xn[4*q+3]=v.w;
            }
            SIG_ROW(xr)
#pragma unroll
            for (int q = 0; q < 4; ++q) {
                float4 v = Ar[4*(r+2)+q];
                xr[4*q+0]=v.x; xr[4*q+1]=v.y; xr[4*q+2]=v.z; xr[4*q+3]=v.w;
            }
            SIG_ROW(xn)
        }
        SIG_ROW(xr)                            // row 126
#undef SIG_ROW

        const float kab = __builtin_bit_cast(float,
            __builtin_amdgcn_readlane(__builtin_bit_cast(int, g_lo), 63));
        acc = fmaf(weight, kab, acc);
    }

    // fused reduction: 4 waves -> LDS -> one atomic per block
    if (lane == 0) red[wid] = acc;
    __syncthreads();
    if (threadIdx.x == 0)
        atomicAdd(out, (red[0] + red[1]) + (red[2] + red[3]));
}

__global__ __launch_bounds__(256) void sig_reduce2(
    const float* __restrict__ v, float* __restrict__ out, int n)
{
    __shared__ float red[256];
    float s = 0.0f;
    for (int i = threadIdx.x; i < n; i += 256) s += v[i];
    red[threadIdx.x] = s;
    __syncthreads();
    for (int st = 128; st > 0; st >>= 1) {
        if (threadIdx.x < st) red[threadIdx.x] += red[threadIdx.x + st];
        __syncthreads();
    }
    if (threadIdx.x == 0) out[0] = red[0];
}

// ---- fallback (ws too small for increment staging): round-1 kernel ----
__global__ __launch_bounds__(64) void sig_pde_kernel(
    const float* __restrict__ X, const float* __restrict__ Y,
    float* __restrict__ ws)
{
    __shared__ float Xs[2048];
    const int T = blockIdx.x;
    const int g = T >> 12;
    const int t = T & 4095;
    const int a = t >> 6, b = t & 63;
    const int lane = threadIdx.x;
    if (g < 2 && a > b) { if (lane == 0) ws[T] = 0.0f; return; }
    const float* P = (g == 1) ? Y : X;
    const float* Q = (g == 0) ? X : Y;
    const float weight = (g == 2) ? (-2.0f / 4096.0f)
                                  : ((a == b ? 1.0f : 2.0f) / 4096.0f);
    {
        const float4* Pa = (const float4*)(P + a * 2048);
        float4* Xs4 = (float4*)Xs;
#pragma unroll
        for (int k = 0; k < 8; ++k) Xs4[lane + (k << 6)] = Pa[lane + (k << 6)];
    }
    __syncthreads();
    {
        float tmp[32];
#pragma unroll
        for (int k = 0; k < 32; ++k) {
            int idx = lane + (k << 6);
            tmp[k] = (idx < 2032) ? (Xs[idx + 16] - Xs[idx]) : 0.0f;
        }
        __syncthreads();
#pragma unroll
        for (int k = 0; k < 32; ++k) {
            int idx = lane + (k << 6);
            if (idx < 2032) Xs[idx] = tmp[k];
        }
    }
    __syncthreads();
    float y0[16], y1[16];
    {
        const float* Qb = Q + b * 2048;
        const int r0 = lane << 1;
        const int r2 = (r0 + 2 > 127) ? 127 : (r0 + 2);
        const float4* A4 = (const float4*)(Qb + r0 * 16);
        const float4* B4 = (const float4*)(Qb + (r0 + 1) * 16);
        const float4* C4 = (const float4*)(Qb + r2 * 16);
#pragma unroll
        for (int q = 0; q < 4; ++q) {
            float4 ra = A4[q], rb = B4[q], rc = C4[q];
            y0[4*q+0] = rb.x - ra.x;  y1[4*q+0] = rc.x - rb.x;
            y0[4*q+1] = rb.y - ra.y;  y1[4*q+1] = rc.y - rb.y;
            y0[4*q+2] = rb.z - ra.z;  y1[4*q+2] = rc.z - rb.z;
            y0[4*q+3] = rb.w - ra.w;  y1[4*q+3] = rc.w - rb.w;
        }
    }
    float g_lo = 1.0f, g_hi = 1.0f;
    const bool last = (lane == 63);
    for (int r = 0; r < 127; ++r) {
        const float* xrow = Xs + r * 16;
        float s0 = -0.5f, s1 = -0.5f, t0 = -0.5f, t1 = -0.5f;
#pragma unroll
        for (int d = 0; d < 16; d += 2) {
            s0 = fmaf(xrow[d], y0[d], s0);   s1 = fmaf(xrow[d+1], y0[d+1], s1);
            t0 = fmaf(xrow[d], y1[d], t0);   t1 = fmaf(xrow[d+1], y1[d+1], t1);
        }
        const float i0 = s0 + s1, i1 = t0 + t1;
        const float gl = wave_shr1(g_hi, 1.0f);
        const float c0 = fmaf(gl, i0, g_lo);
        const float c1 = last ? 0.0f : fmaf(g_lo, i1, g_hi);
        const float S = wave_scan_incl(c0 + c1);
        g_lo = (S - c1) + 1.0f;
        g_hi = S + 1.0f;
    }
    const float kab = __builtin_bit_cast(float,
        __builtin_amdgcn_readlane(__builtin_bit_cast(int, g_lo), 63));
    if (lane == 0) ws[T] = weight * kab;
}

extern "C" void kernel_launch(void* const* d_in, const int* in_sizes, int n_in,
                              void* d_out, int out_size, void* d_ws, size_t ws_size,
                              hipStream_t stream) {
    const float* X = (const float*)d_in[0];
    const float* Y = (const float*)d_in[1];
    float* out = (float*)d_out;
    float* ws  = (float*)d_ws;

    const size_t need = (size_t)(2 * DINC_PER) * sizeof(float);
    if (ws_size >= need) {
        sig_diff<<<254, 256, 0, stream>>>(X, Y, ws, out);
        sig_pde3<<<NBLOCKS3, 256, 0, stream>>>(ws, out);
    } else {
        sig_pde_kernel<<<12288, 64, 0, stream>>>(X, Y, ws);
        sig_reduce2<<<1, 256, 0, stream>>>(ws, out, 12288);
    }
}

// Round 2
// 147.156 us; speedup vs baseline: 1.3931x; 1.3931x over previous
//
#include <hip/hip_runtime.h>

// Signature-kernel MMD via Goursat PDE — round 4.
// Round-3 postmortem: __launch_bounds__(256,8) capped VGPR at 64; the
// asm-pinned 32 dY floats became non-rematerializable -> allocator spilled
// ~10 regs/task to scratch (WRITE_SIZE 66KB -> 20.5MB, VALUBusy 45%,
// dur 94->162us). Per-wave task decode also lost the dX s_load
// scalarization (SGPR 64->32).
// Round-4: (1) cap relaxed to __launch_bounds__(256,4) (VGPR<=128) so the
// pins stay register-resident; allocator still lands 8 waves/SIMD if it
// fits <=64 regs. (2) round-2's proven block-uniform (g,a,b0) decode ->
// dX rows back to SGPRs. (3) grid = exactly 2048 blocks (capacity at 8
// blocks/CU); the 64 overflow block-tasks run as second tasks of blocks
// 0..63 (spread over CUs, ~4us latency-bound tail instead of a second
// dispatch round). (4) ping-pong SGPR row buffers, fused atomic reduce.

#define DINC_PER 130048                         // 64*127*16 floats
#define XY_BLOCKS 1024
#define TRI_BLOCKS 544
#define NBT (XY_BLOCKS + 2 * TRI_BLOCKS)        // 2112 block-tasks
#define NBLOCKS4 2048                           // grid = machine capacity

template <int C, int RM, int BM, bool BC>
__device__ __forceinline__ float dpp0(float x) {
    return __builtin_bit_cast(float, __builtin_amdgcn_update_dpp(
        0, __builtin_bit_cast(int, x), C, RM, BM, BC));
}

// 64-lane inclusive prefix sum, pure VALU (6 dependent adds).
__device__ __forceinline__ float wave_scan_incl(float v) {
    v += dpp0<0x111, 0xf, 0xf, true>(v);   // row_shr:1
    v += dpp0<0x112, 0xf, 0xf, true>(v);   // row_shr:2
    v += dpp0<0x114, 0xf, 0xf, true>(v);   // row_shr:4
    v += dpp0<0x118, 0xf, 0xf, true>(v);   // row_shr:8
    v += dpp0<0x142, 0xa, 0xf, false>(v);  // row_bcast:15 -> rows 1,3
    v += dpp0<0x143, 0xc, 0xf, false>(v);  // row_bcast:31 -> rows 2,3
    return v;
}

// lane l gets lane l-1's x; lane 0 gets `oldv`.
__device__ __forceinline__ float wave_shr1(float x, float oldv) {
    return __builtin_bit_cast(float, __builtin_amdgcn_update_dpp(
        __builtin_bit_cast(int, oldv), __builtin_bit_cast(int, x),
        0x138, 0xf, 0xf, false));          // wave_shr:1
}

// ---- kernel 1: path increments X,Y -> ws (dX at 0, dY at DINC_PER) ----
// Also zeroes out[0] for the fused atomic reduction in sig_pde4.
__global__ __launch_bounds__(256) void sig_diff(
    const float* __restrict__ X, const float* __restrict__ Y,
    float* __restrict__ dInc, float* __restrict__ out)
{
    if (blockIdx.x == 0 && threadIdx.x == 0) out[0] = 0.0f;
    int i = blockIdx.x * 256 + threadIdx.x;   // float4 id, 65024 total
    if (i >= 65024) return;
    int which = (i >= 32512) ? 1 : 0;
    int j = i - which * 32512;
    int a = j / 508;                          // 127*4 float4 per path
    int rq = j - a * 508;                     // r*4 + q
    const float* S = which ? Y : X;
    const float4* p = (const float4*)(S + a * 2048) + rq;
    float4 v0 = p[0], v1 = p[4];              // +16 floats = next row
    float4 d;
    d.x = v1.x - v0.x; d.y = v1.y - v0.y;
    d.z = v1.z - v0.z; d.w = v1.w - v0.w;
    ((float4*)dInc)[i] = d;
}

// ---- kernel 2: PDE. 2048 blocks * 4 waves; block-task BT block-uniform.
// Blocks 0..63 also run overflow block-tasks 2048..2111 as a second task.
__global__ __launch_bounds__(256, 4) void sig_pde4(
    const float* __restrict__ dInc, float* __restrict__ out)
{
    __shared__ float red[4];
    const int wid  = threadIdx.x >> 6;
    const int lane = threadIdx.x & 63;

    float acc = 0.0f;
    const int nt = (blockIdx.x < (NBT - NBLOCKS4)) ? 2 : 1;

#pragma unroll 1
    for (int it = 0; it < nt; ++it) {
        const int BT = it ? (int)(NBLOCKS4 + blockIdx.x) : (int)blockIdx.x;

        // block-uniform decode -> (gram g, a, b0); b = b0 + wave id
        int g, a, b0;
        if (BT < XY_BLOCKS) {                  // XY: dense 64x64
            g = 2; a = BT >> 4; b0 = (BT & 15) << 2;
        } else {                               // XX / YY upper triangles
            int t = BT - XY_BLOCKS; g = 0;
            if (t >= TRI_BLOCKS) { t -= TRI_BLOCKS; g = 1; }
            int aa = 0;
            for (;;) { int nb = (67 - aa) >> 2; if (t < nb) break; t -= nb; ++aa; }
            a = aa; b0 = aa + (t << 2);
        }
        const int b = b0 + wid;

        if (g == 2 || b <= 63) {               // dead triangle waves skip
            const float* dA = (g == 1) ? (dInc + DINC_PER) : dInc;  // rows
            const float* dB = (g == 0) ? dInc : (dInc + DINC_PER);  // cols
            const float weight = (g == 2) ? (-2.0f / 4096.0f)
                                          : ((a == b ? 1.0f : 2.0f) / 4096.0f);

            // per-lane dY rows j=2l, 2l+1 (lane 63's 2nd row masked via c1)
            float ya[16], yb_[16];
            {
                const float* Qb = dB + b * 2032;
                const int j0 = lane << 1;
                const int j1 = (j0 + 1 < 127) ? j0 + 1 : 126;
                const float4* A4 = (const float4*)(Qb + j0 * 16);
                const float4* B4 = (const float4*)(Qb + j1 * 16);
#pragma unroll
                for (int q = 0; q < 4; ++q) {
                    float4 va = A4[q], vb = B4[q];
                    ya[4*q+0]=va.x;  ya[4*q+1]=va.y;  ya[4*q+2]=va.z;  ya[4*q+3]=va.w;
                    yb_[4*q+0]=vb.x; yb_[4*q+1]=vb.y; yb_[4*q+2]=vb.z; yb_[4*q+3]=vb.w;
                }
            }
            // Pin fragments into VGPRs: asm is opaque, so the loads cannot
            // be re-sunk into the row loop (round-2 bug). VGPR cap is 128
            // now, so this pins to registers instead of spilling (round-3).
#pragma unroll
            for (int d = 0; d < 16; ++d)
                asm volatile("" : "+v"(ya[d]), "+v"(yb_[d]));

            // block-uniform dX base -> s_load rows into SGPRs
            const int abase = __builtin_amdgcn_readfirstlane(a * 2032);
            const float4* Ar = (const float4*)(dA + abase);

            float xr[16], xn[16];
#pragma unroll
            for (int q = 0; q < 4; ++q) {
                float4 v = Ar[q];
                xr[4*q+0]=v.x; xr[4*q+1]=v.y; xr[4*q+2]=v.z; xr[4*q+3]=v.w;
            }

            float g_lo = 1.0f, g_hi = 1.0f;    // G[r][2l+1], G[r][2l+2]
            const bool last = (lane == 63);

#define SIG_ROW(XROW)                                                       \
            {                                                               \
                float s0=-0.5f, s1=-0.5f, t0=-0.5f, t1=-0.5f;               \
                _Pragma("unroll")                                           \
                for (int d = 0; d < 16; d += 2) {                           \
                    s0 = fmaf(XROW[d],   ya[d],    s0);                     \
                    s1 = fmaf(XROW[d+1], ya[d+1],  s1);                     \
                    t0 = fmaf(XROW[d],   yb_[d],   t0);                     \
                    t1 = fmaf(XROW[d+1], yb_[d+1], t1);                     \
                }                                                           \
                const float i0 = s0 + s1;      /* inc(r, 2l)   - 1 */       \
                const float i1 = t0 + t1;      /* inc(r, 2l+1) - 1 */       \
                const float gl = wave_shr1(g_hi, 1.0f);  /* G[r][2l] */     \
                const float c0 = fmaf(gl, i0, g_lo);                        \
                const float c1 = last ? 0.0f : fmaf(g_lo, i1, g_hi);        \
                const float S  = wave_scan_incl(c0 + c1);                   \
                g_lo = (S - c1) + 1.0f;                                     \
                g_hi = S + 1.0f;                                            \
            }

            // ping-pong SGPR row buffers: no per-row copy, depth-1 prefetch
#pragma unroll 1
            for (int r = 0; r < 126; r += 2) {
#pragma unroll
                for (int q = 0; q < 4; ++q) {
                    float4 v = Ar[4*(r+1)+q];
                    xn[4*q+0]=v.x; xn[4*q+1]=v.y; xn[4*q+2]=v.z; xn[4*q+3]=v.w;
                }
                SIG_ROW(xr)
#pragma unroll
                for (int q = 0; q < 4; ++q) {
                    float4 v = Ar[4*(r+2)+q];
                    xr[4*q+0]=v.x; xr[4*q+1]=v.y; xr[4*q+2]=v.z; xr[4*q+3]=v.w;
                }
                SIG_ROW(xn)
            }
            SIG_ROW(xr)                        // row 126
#undef SIG_ROW

            const float kab = __builtin_bit_cast(float,
                __builtin_amdgcn_readlane(__builtin_bit_cast(int, g_lo), 63));
            acc = fmaf(weight, kab, acc);
        }
    }

    // fused reduction: 4 waves -> LDS -> one atomic per block
    if (lane == 0) red[wid] = acc;
    __syncthreads();
    if (threadIdx.x == 0)
        atomicAdd(out, (red[0] + red[1]) + (red[2] + red[3]));
}

__global__ __launch_bounds__(256) void sig_reduce2(
    const float* __restrict__ v, float* __restrict__ out, int n)
{
    __shared__ float red[256];
    float s = 0.0f;
    for (int i = threadIdx.x; i < n; i += 256) s += v[i];
    red[threadIdx.x] = s;
    __syncthreads();
    for (int st = 128; st > 0; st >>= 1) {
        if (threadIdx.x < st) red[threadIdx.x] += red[threadIdx.x + st];
        __syncthreads();
    }
    if (threadIdx.x == 0) out[0] = red[0];
}

// ---- fallback (ws too small for increment staging): round-1 kernel ----
__global__ __launch_bounds__(64) void sig_pde_kernel(
    const float* __restrict__ X, const float* __restrict__ Y,
    float* __restrict__ ws)
{
    __shared__ float Xs[2048];
    const int T = blockIdx.x;
    const int g = T >> 12;
    const int t = T & 4095;
    const int a = t >> 6, b = t & 63;
    const int lane = threadIdx.x;
    if (g < 2 && a > b) { if (lane == 0) ws[T] = 0.0f; return; }
    const float* P = (g == 1) ? Y : X;
    const float* Q = (g == 0) ? X : Y;
    const float weight = (g == 2) ? (-2.0f / 4096.0f)
                                  : ((a == b ? 1.0f : 2.0f) / 4096.0f);
    {
        const float4* Pa = (const float4*)(P + a * 2048);
        float4* Xs4 = (float4*)Xs;
#pragma unroll
        for (int k = 0; k < 8; ++k) Xs4[lane + (k << 6)] = Pa[lane + (k << 6)];
    }
    __syncthreads();
    {
        float tmp[32];
#pragma unroll
        for (int k = 0; k < 32; ++k) {
            int idx = lane + (k << 6);
            tmp[k] = (idx < 2032) ? (Xs[idx + 16] - Xs[idx]) : 0.0f;
        }
        __syncthreads();
#pragma unroll
        for (int k = 0; k < 32; ++k) {
            int idx = lane + (k << 6);
            if (idx < 2032) Xs[idx] = tmp[k];
        }
    }
    __syncthreads();
    float y0[16], y1[16];
    {
        const float* Qb = Q + b * 2048;
        const int r0 = lane << 1;
        const int r2 = (r0 + 2 > 127) ? 127 : (r0 + 2);
        const float4* A4 = (const float4*)(Qb + r0 * 16);
        const float4* B4 = (const float4*)(Qb + (r0 + 1) * 16);
        const float4* C4 = (const float4*)(Qb + r2 * 16);
#pragma unroll
        for (int q = 0; q < 4; ++q) {
            float4 ra = A4[q], rb = B4[q], rc = C4[q];
            y0[4*q+0] = rb.x - ra.x;  y1[4*q+0] = rc.x - rb.x;
            y0[4*q+1] = rb.y - ra.y;  y1[4*q+1] = rc.y - rb.y;
            y0[4*q+2] = rb.z - ra.z;  y1[4*q+2] = rc.z - rb.z;
            y0[4*q+3] = rb.w - ra.w;  y1[4*q+3] = rc.w - rb.w;
        }
    }
    float g_lo = 1.0f, g_hi = 1.0f;
    const bool last = (lane == 63);
    for (int r = 0; r < 127; ++r) {
        const float* xrow = Xs + r * 16;
        float s0 = -0.5f, s1 = -0.5f, t0 = -0.5f, t1 = -0.5f;
#pragma unroll
        for (int d = 0; d < 16; d += 2) {
            s0 = fmaf(xrow[d], y0[d], s0);   s1 = fmaf(xrow[d+1], y0[d+1], s1);
            t0 = fmaf(xrow[d], y1[d], t0);   t1 = fmaf(xrow[d+1], y1[d+1], t1);
        }
        const float i0 = s0 + s1, i1 = t0 + t1;
        const float gl = wave_shr1(g_hi, 1.0f);
        const float c0 = fmaf(gl, i0, g_lo);
        const float c1 = last ? 0.0f : fmaf(g_lo, i1, g_hi);
        const float S = wave_scan_incl(c0 + c1);
        g_lo = (S - c1) + 1.0f;
        g_hi = S + 1.0f;
    }
    const float kab = __builtin_bit_cast(float,
        __builtin_amdgcn_readlane(__builtin_bit_cast(int, g_lo), 63));
    if (lane == 0) ws[T] = weight * kab;
}

extern "C" void kernel_launch(void* const* d_in, const int* in_sizes, int n_in,
                              void* d_out, int out_size, void* d_ws, size_t ws_size,
                              hipStream_t stream) {
    const float* X = (const float*)d_in[0];
    const float* Y = (const float*)d_in[1];
    float* out = (float*)d_out;
    float* ws  = (float*)d_ws;

    const size_t need = (size_t)(2 * DINC_PER) * sizeof(float);
    if (ws_size >= need) {
        sig_diff<<<254, 256, 0, stream>>>(X, Y, ws, out);
        sig_pde4<<<NBLOCKS4, 256, 0, stream>>>(ws, out);
    } else {
        sig_pde_kernel<<<12288, 64, 0, stream>>>(X, Y, ws);
        sig_reduce2<<<1, 256, 0, stream>>>(ws, out, 12288);
    }
}

// Round 3
// 143.794 us; speedup vs baseline: 1.4257x; 1.0234x over previous
//
#include <hip/hip_runtime.h>

// Signature-kernel MMD via Goursat PDE — round 5.
// Round-4 postmortem: spill fixed (WRITE 64KB, SGPR 80 = dX scalarized) but
// dur stuck at 99.6us, Occupancy 48%: __launch_bounds__(256,4) let the
// allocator drift past 64 real VGPRs -> 4 blocks/CU -> grid 2048 = TWO full
// rounds (same makespan as round 2). Round-3's cap-64 spill was caused by
// the per-wave decode (SGPR=32: lost scalarization, xr/xn in VGPRs), not by
// the cap itself; block-uniform demand is ~50 VGPRs and fits.
// Round-5: (1) __launch_bounds__(256,8) + block-uniform decode + pins ->
// 8 blocks/CU, one round. (2) packed-fp32 dots: v_pk_fma_f32 via float2
// elementwise fma, 32 -> 16 dot instructions/row (accumulators seeded
// {-0.5,-0.5} preserve the inc-1). Falls back to scalar fmaf harmlessly.

#define DINC_PER 130048                         // 64*127*16 floats
#define XY_BLOCKS 1024
#define TRI_BLOCKS 544
#define NBT (XY_BLOCKS + 2 * TRI_BLOCKS)        // 2112 block-tasks
#define NBLOCKS5 2048                           // grid = capacity @ 8/CU

typedef float v2f __attribute__((ext_vector_type(2)));

__device__ __forceinline__ v2f pkfma(v2f a, v2f b, v2f c) {
#if __has_builtin(__builtin_elementwise_fma)
    return __builtin_elementwise_fma(a, b, c);
#else
    v2f r; r.x = fmaf(a.x, b.x, c.x); r.y = fmaf(a.y, b.y, c.y); return r;
#endif
}

template <int C, int RM, int BM, bool BC>
__device__ __forceinline__ float dpp0(float x) {
    return __builtin_bit_cast(float, __builtin_amdgcn_update_dpp(
        0, __builtin_bit_cast(int, x), C, RM, BM, BC));
}

// 64-lane inclusive prefix sum, pure VALU (6 dependent adds).
__device__ __forceinline__ float wave_scan_incl(float v) {
    v += dpp0<0x111, 0xf, 0xf, true>(v);   // row_shr:1
    v += dpp0<0x112, 0xf, 0xf, true>(v);   // row_shr:2
    v += dpp0<0x114, 0xf, 0xf, true>(v);   // row_shr:4
    v += dpp0<0x118, 0xf, 0xf, true>(v);   // row_shr:8
    v += dpp0<0x142, 0xa, 0xf, false>(v);  // row_bcast:15 -> rows 1,3
    v += dpp0<0x143, 0xc, 0xf, false>(v);  // row_bcast:31 -> rows 2,3
    return v;
}

// lane l gets lane l-1's x; lane 0 gets `oldv`.
__device__ __forceinline__ float wave_shr1(float x, float oldv) {
    return __builtin_bit_cast(float, __builtin_amdgcn_update_dpp(
        __builtin_bit_cast(int, oldv), __builtin_bit_cast(int, x),
        0x138, 0xf, 0xf, false));          // wave_shr:1
}

// ---- kernel 1: path increments X,Y -> ws (dX at 0, dY at DINC_PER) ----
// Also zeroes out[0] for the fused atomic reduction in sig_pde5.
__global__ __launch_bounds__(256) void sig_diff(
    const float* __restrict__ X, const float* __restrict__ Y,
    float* __restrict__ dInc, float* __restrict__ out)
{
    if (blockIdx.x == 0 && threadIdx.x == 0) out[0] = 0.0f;
    int i = blockIdx.x * 256 + threadIdx.x;   // float4 id, 65024 total
    if (i >= 65024) return;
    int which = (i >= 32512) ? 1 : 0;
    int j = i - which * 32512;
    int a = j / 508;                          // 127*4 float4 per path
    int rq = j - a * 508;                     // r*4 + q
    const float* S = which ? Y : X;
    const float4* p = (const float4*)(S + a * 2048) + rq;
    float4 v0 = p[0], v1 = p[4];              // +16 floats = next row
    float4 d;
    d.x = v1.x - v0.x; d.y = v1.y - v0.y;
    d.z = v1.z - v0.z; d.w = v1.w - v0.w;
    ((float4*)dInc)[i] = d;
}

// ---- kernel 2: PDE. 2048 blocks * 4 waves; block-task BT block-uniform.
// Blocks 0..63 also run overflow block-tasks 2048..2111 as a second task.
__global__ __launch_bounds__(256, 8) void sig_pde5(
    const float* __restrict__ dInc, float* __restrict__ out)
{
    __shared__ float red[4];
    const int wid  = threadIdx.x >> 6;
    const int lane = threadIdx.x & 63;

    float acc = 0.0f;
    const int nt = (blockIdx.x < (NBT - NBLOCKS5)) ? 2 : 1;

#pragma unroll 1
    for (int it = 0; it < nt; ++it) {
        const int BT = it ? (int)(NBLOCKS5 + blockIdx.x) : (int)blockIdx.x;

        // block-uniform decode -> (gram g, a, b0); b = b0 + wave id
        int g, a, b0;
        if (BT < XY_BLOCKS) {                  // XY: dense 64x64
            g = 2; a = BT >> 4; b0 = (BT & 15) << 2;
        } else {                               // XX / YY upper triangles
            int t = BT - XY_BLOCKS; g = 0;
            if (t >= TRI_BLOCKS) { t -= TRI_BLOCKS; g = 1; }
            int aa = 0;
            for (;;) { int nb = (67 - aa) >> 2; if (t < nb) break; t -= nb; ++aa; }
            a = aa; b0 = aa + (t << 2);
        }
        const int b = b0 + wid;

        if (g == 2 || b <= 63) {               // dead triangle waves skip
            const float* dA = (g == 1) ? (dInc + DINC_PER) : dInc;  // rows
            const float* dB = (g == 0) ? dInc : (dInc + DINC_PER);  // cols
            const float weight = (g == 2) ? (-2.0f / 4096.0f)
                                          : ((a == b ? 1.0f : 2.0f) / 4096.0f);

            // per-lane dY rows j=2l, 2l+1 (lane 63's 2nd row masked via c1)
            v2f ya2[8], yb2[8];
            {
                const float* Qb = dB + b * 2032;
                const int j0 = lane << 1;
                const int j1 = (j0 + 1 < 127) ? j0 + 1 : 126;
                const float4* A4 = (const float4*)(Qb + j0 * 16);
                const float4* B4 = (const float4*)(Qb + j1 * 16);
#pragma unroll
                for (int q = 0; q < 4; ++q) {
                    float4 va = A4[q], vb = B4[q];
                    ya2[2*q+0] = (v2f){va.x, va.y};
                    ya2[2*q+1] = (v2f){va.z, va.w};
                    yb2[2*q+0] = (v2f){vb.x, vb.y};
                    yb2[2*q+1] = (v2f){vb.z, vb.w};
                }
            }
            // Pin fragments into VGPR pairs (opaque to the scheduler: loads
            // cannot be re-sunk into the row loop; round-2 reload bug).
#pragma unroll
            for (int d = 0; d < 8; ++d)
                asm volatile("" : "+v"(ya2[d]), "+v"(yb2[d]));

            // block-uniform dX base -> s_load rows into SGPR pairs
            const int abase = __builtin_amdgcn_readfirstlane(a * 2032);
            const float4* Ar = (const float4*)(dA + abase);

            v2f xr2[8], xn2[8];
#pragma unroll
            for (int q = 0; q < 4; ++q) {
                float4 v = Ar[q];
                xr2[2*q+0] = (v2f){v.x, v.y};
                xr2[2*q+1] = (v2f){v.z, v.w};
            }

            float g_lo = 1.0f, g_hi = 1.0f;    // G[r][2l+1], G[r][2l+2]
            const bool last = (lane == 63);

#define SIG_ROW(XROW)                                                       \
            {                                                               \
                v2f s2 = (v2f){-0.5f, -0.5f};  /* seeds sum to the -1 */    \
                v2f t2 = (v2f){-0.5f, -0.5f};                               \
                _Pragma("unroll")                                           \
                for (int k = 0; k < 8; ++k) {                               \
                    s2 = pkfma(XROW[k], ya2[k], s2);                        \
                    t2 = pkfma(XROW[k], yb2[k], t2);                        \
                }                                                           \
                const float i0 = s2.x + s2.y;  /* inc(r, 2l)   - 1 */       \
                const float i1 = t2.x + t2.y;  /* inc(r, 2l+1) - 1 */       \
                const float gl = wave_shr1(g_hi, 1.0f);  /* G[r][2l] */     \
                const float c0 = fmaf(gl, i0, g_lo);                        \
                const float c1 = last ? 0.0f : fmaf(g_lo, i1, g_hi);        \
                const float S  = wave_scan_incl(c0 + c1);                   \
                g_lo = (S - c1) + 1.0f;                                     \
                g_hi = S + 1.0f;                                            \
            }

            // ping-pong SGPR row buffers: no per-row copy, depth-1 prefetch
#pragma unroll 1
            for (int r = 0; r < 126; r += 2) {
#pragma unroll
                for (int q = 0; q < 4; ++q) {
                    float4 v = Ar[4*(r+1)+q];
                    xn2[2*q+0] = (v2f){v.x, v.y};
                    xn2[2*q+1] = (v2f){v.z, v.w};
                }
                SIG_ROW(xr2)
#pragma unroll
                for (int q = 0; q < 4; ++q) {
                    float4 v = Ar[4*(r+2)+q];
                    xr2[2*q+0] = (v2f){v.x, v.y};
                    xr2[2*q+1] = (v2f){v.z, v.w};
                }
                SIG_ROW(xn2)
            }
            SIG_ROW(xr2)                       // row 126
#undef SIG_ROW

            const float kab = __builtin_bit_cast(float,
                __builtin_amdgcn_readlane(__builtin_bit_cast(int, g_lo), 63));
            acc = fmaf(weight, kab, acc);
        }
    }

    // fused reduction: 4 waves -> LDS -> one atomic per block
    if (lane == 0) red[wid] = acc;
    __syncthreads();
    if (threadIdx.x == 0)
        atomicAdd(out, (red[0] + red[1]) + (red[2] + red[3]));
}

__global__ __launch_bounds__(256) void sig_reduce2(
    const float* __restrict__ v, float* __restrict__ out, int n)
{
    __shared__ float red[256];
    float s = 0.0f;
    for (int i = threadIdx.x; i < n; i += 256) s += v[i];
    red[threadIdx.x] = s;
    __syncthreads();
    for (int st = 128; st > 0; st >>= 1) {
        if (threadIdx.x < st) red[threadIdx.x] += red[threadIdx.x + st];
        __syncthreads();
    }
    if (threadIdx.x == 0) out[0] = red[0];
}

// ---- fallback (ws too small for increment staging): round-1 kernel ----
__global__ __launch_bounds__(64) void sig_pde_kernel(
    const float* __restrict__ X, const float* __restrict__ Y,
    float* __restrict__ ws)
{
    __shared__ float Xs[2048];
    const int T = blockIdx.x;
    const int g = T >> 12;
    const int t = T & 4095;
    const int a = t >> 6, b = t & 63;
    const int lane = threadIdx.x;
    if (g < 2 && a > b) { if (lane == 0) ws[T] = 0.0f; return; }
    const float* P = (g == 1) ? Y : X;
    const float* Q = (g == 0) ? X : Y;
    const float weight = (g == 2) ? (-2.0f / 4096.0f)
                                  : ((a == b ? 1.0f : 2.0f) / 4096.0f);
    {
        const float4* Pa = (const float4*)(P + a * 2048);
        float4* Xs4 = (float4*)Xs;
#pragma unroll
        for (int k = 0; k < 8; ++k) Xs4[lane + (k << 6)] = Pa[lane + (k << 6)];
    }
    __syncthreads();
    {
        float tmp[32];
#pragma unroll
        for (int k = 0; k < 32; ++k) {
            int idx = lane + (k << 6);
            tmp[k] = (idx < 2032) ? (Xs[idx + 16] - Xs[idx]) : 0.0f;
        }
        __syncthreads();
#pragma unroll
        for (int k = 0; k < 32; ++k) {
            int idx = lane + (k << 6);
            if (idx < 2032) Xs[idx] = tmp[k];
        }
    }
    __syncthreads();
    float y0[16], y1[16];
    {
        const float* Qb = Q + b * 2048;
        const int r0 = lane << 1;
        const int r2 = (r0 + 2 > 127) ? 127 : (r0 + 2);
        const float4* A4 = (const float4*)(Qb + r0 * 16);
        const float4* B4 = (const float4*)(Qb + (r0 + 1) * 16);
        const float4* C4 = (const float4*)(Qb + r2 * 16);
#pragma unroll
        for (int q = 0; q < 4; ++q) {
            float4 ra = A4[q], rb = B4[q], rc = C4[q];
            y0[4*q+0] = rb.x - ra.x;  y1[4*q+0] = rc.x - rb.x;
            y0[4*q+1] = rb.y - ra.y;  y1[4*q+1] = rc.y - rb.y;
            y0[4*q+2] = rb.z - ra.z;  y1[4*q+2] = rc.z - rb.z;
            y0[4*q+3] = rb.w - ra.w;  y1[4*q+3] = rc.w - rb.w;
        }
    }
    float g_lo = 1.0f, g_hi = 1.0f;
    const bool last = (lane == 63);
    for (int r = 0; r < 127; ++r) {
        const float* xrow = Xs + r * 16;
        float s0 = -0.5f, s1 = -0.5f, t0 = -0.5f, t1 = -0.5f;
#pragma unroll
        for (int d = 0; d < 16; d += 2) {
            s0 = fmaf(xrow[d], y0[d], s0);   s1 = fmaf(xrow[d+1], y0[d+1], s1);
            t0 = fmaf(xrow[d], y1[d], t0);   t1 = fmaf(xrow[d+1], y1[d+1], t1);
        }
        const float i0 = s0 + s1, i1 = t0 + t1;
        const float gl = wave_shr1(g_hi, 1.0f);
        const float c0 = fmaf(gl, i0, g_lo);
        const float c1 = last ? 0.0f : fmaf(g_lo, i1, g_hi);
        const float S = wave_scan_incl(c0 + c1);
        g_lo = (S - c1) + 1.0f;
        g_hi = S + 1.0f;
    }
    const float kab = __builtin_bit_cast(float,
        __builtin_amdgcn_readlane(__builtin_bit_cast(int, g_lo), 63));
    if (lane == 0) ws[T] = weight * kab;
}

extern "C" void kernel_launch(void* const* d_in, const int* in_sizes, int n_in,
                              void* d_out, int out_size, void* d_ws, size_t ws_size,
                              hipStream_t stream) {
    const float* X = (const float*)d_in[0];
    const float* Y = (const float*)d_in[1];
    float* out = (float*)d_out;
    float* ws  = (float*)d_ws;

    const size_t need = (size_t)(2 * DINC_PER) * sizeof(float);
    if (ws_size >= need) {
        sig_diff<<<254, 256, 0, stream>>>(X, Y, ws, out);
        sig_pde5<<<NBLOCKS5, 256, 0, stream>>>(ws, out);
    } else {
        sig_pde_kernel<<<12288, 64, 0, stream>>>(X, Y, ws);
        sig_reduce2<<<1, 256, 0, stream>>>(ws, out, 12288);
    }
}